// Round 2
// baseline (313.667 us; speedup 1.0000x reference)
//
#include <hip/hip_runtime.h>

#define HW 3136
#define NB 8
#define CD 128
// C^-0.5 * log2(e), folded into the Q projection so attn can use exp2 directly
#define QSCALE 0.12751750206f

typedef __attribute__((ext_vector_type(8))) short short8;
typedef __attribute__((ext_vector_type(4))) float floatx4;
typedef __attribute__((ext_vector_type(4))) unsigned short ushort4v;

static __device__ __forceinline__ unsigned short f2b(float f){
  union { float f; unsigned u; } v; v.f = f;
  unsigned r = v.u + 0x7FFFu + ((v.u >> 16) & 1u);
  return (unsigned short)(r >> 16);
}
static __device__ __forceinline__ float b2f(unsigned short h){
  union { unsigned u; float f; } v; v.u = ((unsigned)h) << 16;
  return v.f;
}

// ---------------------------------------------------------------------------
// 1x1 conv projections via MFMA: Y[b,hw,o] = sum_c X[b,c,hw] * W[o,c] + bias[o]
// job 0: Q = (s*Wq+bq)*QSCALE  -> [b][hw][c]
// job 1: K1 = t1*Wk+bk         -> [b][hw][c]
// job 2: V1 = t1*Wv+bv         -> [b][c][hw]  (channel-major)
// job 3: K2 = t2*Wk+bk         -> [b][hw][c]
// job 4: V2 = t2*Wv+bv         -> [b][c][hw]
// ---------------------------------------------------------------------------
__global__ __launch_bounds__(256) void proj_kernel(
    const float* __restrict__ s, const float* __restrict__ t1, const float* __restrict__ t2,
    const float* __restrict__ wq, const float* __restrict__ bq,
    const float* __restrict__ wk, const float* __restrict__ bk,
    const float* __restrict__ wv, const float* __restrict__ bv,
    unsigned short* __restrict__ qkv)
{
  __shared__ __align__(16) unsigned short WL[CD][136];   // W bf16 [o][c], pad->floor conflicts
  __shared__ __align__(16) unsigned short xsT[64][136];  // X^T bf16 [hw_local][c]
  const int job = blockIdx.z;
  const float* x; const float* w; const float* bias; float scl; int cmajor; size_t dstoff;
  switch(job){
    case 0: x=s;  w=wq; bias=bq; scl=QSCALE; cmajor=0; dstoff=0; break;
    case 1: x=t1; w=wk; bias=bk; scl=1.f;    cmajor=0; dstoff=1; break;
    case 2: x=t1; w=wv; bias=bv; scl=1.f;    cmajor=1; dstoff=2; break;
    case 3: x=t2; w=wk; bias=bk; scl=1.f;    cmajor=0; dstoff=3; break;
    default:x=t2; w=wv; bias=bv; scl=1.f;    cmajor=1; dstoff=4; break;
  }
  const size_t TS = (size_t)NB*HW*CD;
  const int b   = blockIdx.y;
  const int hw0 = blockIdx.x * 64;
  const int tid = threadIdx.x;

  // stage W (f32 -> bf16, rounded)
  for (int i = 0; i < 16; i++){
    int flat = tid + i*256;                 // o*32 + cq/4
    int o = flat >> 5, cq = (flat & 31)*4;
    floatx4 wv4 = *(const floatx4*)(w + (size_t)o*CD + cq);
    ushort4v pk;
    for (int j=0;j<4;j++) pk[j] = f2b(wv4[j]);
    *(ushort4v*)&WL[o][cq] = pk;
  }
  // stage X^T (transpose during store; scalar b16 writes, one-time cost)
  const float* xb = x + (size_t)b*CD*HW + hw0;
  for (int i = 0; i < 8; i++){
    int flat = (tid + i*256)*4;             // c*64 + hh
    int c = flat >> 6, hh = flat & 63;
    floatx4 xv = *(const floatx4*)(xb + (size_t)c*HW + hh);
    for (int j=0;j<4;j++) xsT[hh+j][c] = f2b(xv[j]);
  }
  __syncthreads();

  const int m = tid & 15, quad = (tid >> 4) & 3, wv_ = tid >> 6;
  short8 af[4];
  for (int dk=0;dk<4;dk++)
    af[dk] = *(const short8*)&xsT[wv_*16 + m][dk*32 + quad*8];
  float bb[8];
  for (int nt=0;nt<8;nt++) bb[nt] = bias[nt*16 + m];

  unsigned short* dstK = qkv + dstoff*TS + ((size_t)b*HW + hw0)*CD;
  unsigned short* dstV = qkv + dstoff*TS + (size_t)b*CD*HW;
  for (int nt=0;nt<8;nt++){
    floatx4 acc = {bb[nt],bb[nt],bb[nt],bb[nt]};
    for (int dk=0;dk<4;dk++){
      short8 bf = *(const short8*)&WL[nt*16 + m][dk*32 + quad*8];
      acc = __builtin_amdgcn_mfma_f32_16x16x32_bf16(af[dk], bf, acc, 0,0,0);
    }
    if (!cmajor){
      // D row = hw = wv*16+quad*4+r, col = o = nt*16+m
      for (int r=0;r<4;r++)
        dstK[(size_t)(wv_*16 + quad*4 + r)*CD + nt*16 + m] = f2b(acc[r]*scl);
    } else {
      ushort4v pk;
      for (int r=0;r<4;r++) pk[r] = f2b(acc[r]*scl);
      *(ushort4v*)&dstV[(size_t)(nt*16 + m)*HW + hw0 + wv_*16 + quad*4] = pk;
    }
  }
}

// ---------------------------------------------------------------------------
// Flash attention (no-max-subtraction softmax; scores pre-scaled to log2 domain).
// Block = 4 waves, wave owns 16 q rows.
// Swapped QK^T: S^T = mfma(K, Q) so each lane owns one q-row slice (q = lane&15);
// P never touches LDS — packed to bf16 in-register and routed into the PV
// B-fragment (P^T) with 16 shuffles. PV computes O^T = V^T * P^T.
// LDS = 35840 B -> 4 blocks/CU: all 784 blocks co-resident (was 3/CU -> 768
// resident + 16-block straggler tail ~2x makespan; rocprof occupancy 21% ~
// (37.5+1)/2 was the smoking gun).
// ---------------------------------------------------------------------------
#define KL_E (64*136)     // K tile [64][136]
#define VL_E (128*72)     // V tile [128][72]  ([c][k])

__global__ __launch_bounds__(256,4) void attn_kernel(
    const unsigned short* __restrict__ qkv,
    unsigned short* __restrict__ Og)
{
  __shared__ __align__(16) unsigned short smem[KL_E + VL_E]; // 35840 B
  unsigned short (*Kl)[136] = (unsigned short(*)[136])smem;
  unsigned short (*Vl)[72]  = (unsigned short(*)[72])(smem + KL_E);

  const int qt = blockIdx.x;
  const int b  = blockIdx.y;
  const int t  = blockIdx.z;
  const size_t TS = (size_t)NB*HW*CD;
  const unsigned short* Q = qkv + (size_t)b*HW*CD;
  const unsigned short* K = qkv + TS*(size_t)(1 + 2*t) + (size_t)b*HW*CD;
  const unsigned short* V = qkv + TS*(size_t)(2 + 2*t) + (size_t)b*CD*HW;

  const int tid  = threadIdx.x;
  const int wv_  = tid >> 6;
  const int lane = tid & 63;
  const int m    = lane & 15;
  const int quad = lane >> 4;
  const int q0   = qt*64 + wv_*16;

  short8 qf[4];   // B-operand now: col = q = lane&15 (same load as before)
  {
    const unsigned short* qr = Q + (size_t)(q0+m)*CD + quad*8;
    for (int dk=0;dk<4;dk++) qf[dk] = *(const short8*)(qr + dk*32);
  }
  floatx4 Oc[8];  // O^T accum: Oc[ct][r] = O^T[c=ct*16+quad*4+r][q=q0+m]
  for (int i=0;i<8;i++) Oc[i] = (floatx4)0.f;
  float lr = 0.f; // per-lane softmax denominator partial for q = q0+m

  // per-thread staging addresses
  const unsigned short* kg = K + (size_t)(tid>>4)*CD + (tid&15)*8;
  const unsigned short* vg = V + (size_t)(tid>>3)*HW + (tid&7)*8;
  unsigned short* klds = &Kl[tid>>4][(tid&15)*8];
  unsigned short* vlds = &Vl[tid>>3][(tid&7)*8];

  short8 kpre[4], vpre[4];
  for (int i=0;i<4;i++) kpre[i] = *(const short8*)(kg + (size_t)i*16*CD);
  for (int i=0;i<4;i++) vpre[i] = *(const short8*)(vg + (size_t)i*32*HW);

  // shuffle source lanes for the P^T B-fragment assembly:
  // target word (kk,w) wants k = 32kk + 8*quad + 2w{,+1}
  //   -> src lane quad' = (2*quad + (w>>1)) & 3 (same m), src word nt' = 2kk + (quad>>1)
  const int sl0 = (((quad<<1)    ) & 3)*16 + m;   // words w = 0,1
  const int sl1 = (((quad<<1) + 1) & 3)*16 + m;   // words w = 2,3
  const bool hiq = (quad >= 2);                   // selects nt' = 2kk+1 source words

  for (int kt = 0; kt < HW/64; kt++){
    __syncthreads();                       // all waves done reading prev tile
    for (int i=0;i<4;i++) *(short8*)(klds + i*16*136) = kpre[i];
    for (int i=0;i<4;i++) *(short8*)(vlds + i*32*72)  = vpre[i];
    __syncthreads();
    if (kt < HW/64 - 1){                   // prefetch next tile during compute
      kg += 64*CD; vg += 64;
      for (int i=0;i<4;i++) kpre[i] = *(const short8*)(kg + (size_t)i*16*CD);
      for (int i=0;i<4;i++) vpre[i] = *(const short8*)(vg + (size_t)i*32*HW);
    }

    // S^T[k][q]: A = K-tile rows (k), B = Q (cols = q). Lane holds
    // k = nt*16 + quad*4 + r, q = q0 + m. Scores already in log2 domain.
    unsigned pw[8];                        // pw[nt*2+a] = bf16(p[2a+1])<<16 | bf16(p[2a])
    for (int nt=0;nt<4;nt++){
      floatx4 acc = (floatx4)0.f;
      for (int dk=0;dk<4;dk++){
        short8 kf = *(const short8*)&Kl[nt*16 + m][dk*32 + quad*8];
        acc = __builtin_amdgcn_mfma_f32_16x16x32_bf16(kf, qf[dk], acc, 0,0,0);
      }
      union { float f; unsigned u; } c0, c1, c2, c3;
      c0.f = __builtin_amdgcn_exp2f(acc[0]);
      c1.f = __builtin_amdgcn_exp2f(acc[1]);
      c2.f = __builtin_amdgcn_exp2f(acc[2]);
      c3.f = __builtin_amdgcn_exp2f(acc[3]);
      lr += (c0.f + c1.f) + (c2.f + c3.f);
      pw[nt*2+0] = (c1.u & 0xFFFF0000u) | (c0.u >> 16);  // truncate-pack (as before)
      pw[nt*2+1] = (c3.u & 0xFFFF0000u) | (c2.u >> 16);
    }

    // assemble P^T B-fragments fully in-register (16 shuffles, no LDS, no barrier)
    short8 pf[2];
    for (int kk=0;kk<2;kk++){
      union { unsigned u[4]; short8 s; } bf_;
      for (int w=0;w<4;w++){
        int sl = (w>>1) ? sl1 : sl0;
        int lo = __shfl((int)pw[4*kk     + (w&1)], sl, 64);  // src nt' = 2kk
        int hi = __shfl((int)pw[4*kk + 2 + (w&1)], sl, 64);  // src nt' = 2kk+1
        bf_.u[w] = hiq ? (unsigned)hi : (unsigned)lo;
      }
      pf[kk] = bf_.s;
    }

    // PV: O^T[c][q] += V^T[c][k] * P^T[k][q]; V^T is exactly the channel-major Vl
    for (int ct=0;ct<8;ct++){
      floatx4 o = Oc[ct];
      for (int kk=0;kk<2;kk++){
        short8 vf = *(const short8*)&Vl[ct*16 + m][kk*32 + quad*8];
        o = __builtin_amdgcn_mfma_f32_16x16x32_bf16(vf, pf[kk], o, 0,0,0);
      }
      Oc[ct] = o;
    }
  }

  // denominator: sum the 4 quad-partials (each lane then has total for q = q0+m)
  lr += __shfl_xor(lr, 16, 64);
  lr += __shfl_xor(lr, 32, 64);
  const float inv = 1.f / lr;

  __syncthreads();                         // done with K/V LDS; reuse as f32 staging
  float* stg = ((float*)smem) + wv_*(16*132);
  for (int ct=0;ct<8;ct++){
    floatx4 vv;
    for (int r=0;r<4;r++) vv[r] = Oc[ct][r]*inv;
    // transpose O^T -> stg[q-local][c]; 4 r-values are contiguous in c -> b128 store
    *(floatx4*)&stg[m*132 + ct*16 + quad*4] = vv;
  }
  __syncthreads();
  unsigned short* ob = Og + ((size_t)t*NB + b)*HW*CD + (size_t)q0*CD;
  for (int row=0; row<16; row++){
    float v0 = stg[row*132 + 2*lane];
    float v1 = stg[row*132 + 2*lane + 1];
    unsigned short pk[2] = {f2b(v0), f2b(v1)};
    *(unsigned int*)&ob[(size_t)row*CD + 2*lane] = *(const unsigned int*)pk;
  }
}

// ---------------------------------------------------------------------------
// out[b,c,hw] = s[b,c,hw] + 0.5*(O1[b,hw,c] + O2[b,hw,c])
// ---------------------------------------------------------------------------
__global__ __launch_bounds__(256) void combine_kernel(
    const float* __restrict__ s, const unsigned short* __restrict__ Og,
    float* __restrict__ out)
{
  __shared__ float T[32][129];
  const int b   = blockIdx.y;
  const int hw0 = blockIdx.x * 32;
  const int tid = threadIdx.x;
  const unsigned short* O1 = Og + ((size_t)b*HW + hw0)*CD;
  const unsigned short* O2 = O1 + (size_t)NB*HW*CD;
  for (int i=0;i<2;i++){
    int flat = (tid + i*256)*8;
    int row = flat >> 7, col = flat & 127;
    short8 a  = *(const short8*)(O1 + (size_t)row*CD + col);
    short8 c2 = *(const short8*)(O2 + (size_t)row*CD + col);
    for (int j=0;j<8;j++)
      T[row][col+j] = 0.5f*(b2f((unsigned short)a[j]) + b2f((unsigned short)c2[j]));
  }
  __syncthreads();
  const int c  = tid >> 1;
  const int h0 = (tid & 1)*16;
  const float* sr = s   + ((size_t)b*CD + c)*HW + hw0 + h0;
  float*     orow = out + ((size_t)b*CD + c)*HW + hw0 + h0;
  for (int j0=0;j0<16;j0+=4){
    floatx4 sv = *(const floatx4*)(sr + j0);
    floatx4 ov;
    for (int jj=0;jj<4;jj++) ov[jj] = sv[jj] + T[h0+j0+jj][c];
    *(floatx4*)(orow + j0) = ov;
  }
}

extern "C" void kernel_launch(void* const* d_in, const int* in_sizes, int n_in,
                              void* d_out, int out_size, void* d_ws, size_t ws_size,
                              hipStream_t stream)
{
  const float* s  = (const float*)d_in[0];
  const float* t1 = (const float*)d_in[1];
  const float* t2 = (const float*)d_in[2];
  const float* wq = (const float*)d_in[3];
  const float* bq = (const float*)d_in[4];
  const float* wk = (const float*)d_in[5];
  const float* bk = (const float*)d_in[6];
  const float* wv = (const float*)d_in[7];
  const float* bv = (const float*)d_in[8];
  float* out = (float*)d_out;

  unsigned short* qkv = (unsigned short*)d_ws;
  unsigned short* Og  = qkv + (size_t)5*NB*HW*CD;

  hipLaunchKernelGGL(proj_kernel,    dim3(49,8,5), dim3(256), 0, stream,
                     s,t1,t2,wq,bq,wk,bk,wv,bv,qkv);
  hipLaunchKernelGGL(attn_kernel,    dim3(49,8,2), dim3(256), 0, stream, qkv, Og);
  hipLaunchKernelGGL(combine_kernel, dim3(98,8),   dim3(256), 0, stream, s, Og, out);
}

// Round 3
// 287.433 us; speedup vs baseline: 1.0913x; 1.0913x over previous
//
#include <hip/hip_runtime.h>

#define HW 3136
#define NB 8
#define CD 128
#define NT (HW/64)
// C^-0.5 * log2(e), folded into the Q projection so attn can use exp2 directly
#define QSCALE 0.12751750206f

typedef __attribute__((ext_vector_type(8))) short short8;
typedef __attribute__((ext_vector_type(4))) short short4v;
typedef __attribute__((ext_vector_type(4))) float floatx4;
typedef __attribute__((ext_vector_type(4))) unsigned short ushort4v;

static __device__ __forceinline__ unsigned short f2b(float f){
  union { float f; unsigned u; } v; v.f = f;
  unsigned r = v.u + 0x7FFFu + ((v.u >> 16) & 1u);
  return (unsigned short)(r >> 16);
}
static __device__ __forceinline__ float b2f(unsigned short h){
  union { unsigned u; float f; } v; v.u = ((unsigned)h) << 16;
  return v.f;
}

// K=16 bf16 MFMA: builtin spelling differs across ROCm versions; hedge.
#if __has_builtin(__builtin_amdgcn_mfma_f32_16x16x16bf16_1k)
#define MFMA16(a,b,c) __builtin_amdgcn_mfma_f32_16x16x16bf16_1k(a,b,c,0,0,0)
#elif __has_builtin(__builtin_amdgcn_mfma_f32_16x16x16_bf16)
#define MFMA16(a,b,c) __builtin_amdgcn_mfma_f32_16x16x16_bf16(a,b,c,0,0,0)
#else
static __device__ __forceinline__ floatx4 mfma16_asm(short4v a, short4v b, floatx4 c){
  floatx4 d;
  asm volatile("v_mfma_f32_16x16x16_bf16 %0, %1, %2, %3\n\ts_nop 7\n\ts_nop 7"
               : "=v"(d) : "v"(a), "v"(b), "v"(c));
  return d;
}
#define MFMA16(a,b,c) mfma16_asm(a,b,c)
#endif

// ---------------------------------------------------------------------------
// 1x1 conv projections via MFMA: Y[b,hw,o] = sum_c X[b,c,hw] * W[o,c] + bias[o]
// (unchanged — control kernel)
// ---------------------------------------------------------------------------
__global__ __launch_bounds__(256) void proj_kernel(
    const float* __restrict__ s, const float* __restrict__ t1, const float* __restrict__ t2,
    const float* __restrict__ wq, const float* __restrict__ bq,
    const float* __restrict__ wk, const float* __restrict__ bk,
    const float* __restrict__ wv, const float* __restrict__ bv,
    unsigned short* __restrict__ qkv)
{
  __shared__ __align__(16) unsigned short WL[CD][136];
  __shared__ __align__(16) unsigned short xsT[64][136];
  const int job = blockIdx.z;
  const float* x; const float* w; const float* bias; float scl; int cmajor; size_t dstoff;
  switch(job){
    case 0: x=s;  w=wq; bias=bq; scl=QSCALE; cmajor=0; dstoff=0; break;
    case 1: x=t1; w=wk; bias=bk; scl=1.f;    cmajor=0; dstoff=1; break;
    case 2: x=t1; w=wv; bias=bv; scl=1.f;    cmajor=1; dstoff=2; break;
    case 3: x=t2; w=wk; bias=bk; scl=1.f;    cmajor=0; dstoff=3; break;
    default:x=t2; w=wv; bias=bv; scl=1.f;    cmajor=1; dstoff=4; break;
  }
  const size_t TS = (size_t)NB*HW*CD;
  const int b   = blockIdx.y;
  const int hw0 = blockIdx.x * 64;
  const int tid = threadIdx.x;

  for (int i = 0; i < 16; i++){
    int flat = tid + i*256;
    int o = flat >> 5, cq = (flat & 31)*4;
    floatx4 wv4 = *(const floatx4*)(w + (size_t)o*CD + cq);
    ushort4v pk;
    for (int j=0;j<4;j++) pk[j] = f2b(wv4[j]);
    *(ushort4v*)&WL[o][cq] = pk;
  }
  const float* xb = x + (size_t)b*CD*HW + hw0;
  for (int i = 0; i < 8; i++){
    int flat = (tid + i*256)*4;
    int c = flat >> 6, hh = flat & 63;
    floatx4 xv = *(const floatx4*)(xb + (size_t)c*HW + hh);
    for (int j=0;j<4;j++) xsT[hh+j][c] = f2b(xv[j]);
  }
  __syncthreads();

  const int m = tid & 15, quad = (tid >> 4) & 3, wv_ = tid >> 6;
  short8 af[4];
  for (int dk=0;dk<4;dk++)
    af[dk] = *(const short8*)&xsT[wv_*16 + m][dk*32 + quad*8];
  float bb[8];
  for (int nt=0;nt<8;nt++) bb[nt] = bias[nt*16 + m];

  unsigned short* dstK = qkv + dstoff*TS + ((size_t)b*HW + hw0)*CD;
  unsigned short* dstV = qkv + dstoff*TS + (size_t)b*CD*HW;
  for (int nt=0;nt<8;nt++){
    floatx4 acc = {bb[nt],bb[nt],bb[nt],bb[nt]};
    for (int dk=0;dk<4;dk++){
      short8 bf = *(const short8*)&WL[nt*16 + m][dk*32 + quad*8];
      acc = __builtin_amdgcn_mfma_f32_16x16x32_bf16(af[dk], bf, acc, 0,0,0);
    }
    if (!cmajor){
      for (int r=0;r<4;r++)
        dstK[(size_t)(wv_*16 + quad*4 + r)*CD + nt*16 + m] = f2b(acc[r]*scl);
    } else {
      ushort4v pk;
      for (int r=0;r<4;r++) pk[r] = f2b(acc[r]*scl);
      *(ushort4v*)&dstV[(size_t)(nt*16 + m)*HW + hw0 + wv_*16 + quad*4] = pk;
    }
  }
}

// ---------------------------------------------------------------------------
// Flash attention, k-split edition.
// Model (R2 post-mortem): kernel is LDS-pipe-BW-bound (176KB/block-iter matched
// measured 9.1K cyc/block-iter). Fix: waves split the 64-k tile 4 ways.
//  - QK: wave wv computes S^T[wv's 16k][64q] -> K tile read ONCE per block.
//  - PV uses 16x16x16 MFMA: the S^T D-fragment (row=quad*4+r, col=m) IS the
//    K=16 B-operand fragment -> each lane's own p feeds PV. No shuffles, no
//    P-LDS. V read ONCE per block (b64 A-frags).
//  - Each wave holds a k-partial O^T[128c][64q] (128 VGPR); partials + softmax
//    denominators summed across waves in a one-time epilogue.
// LDS traffic: 176KB -> 64KB per block-iter.
// ---------------------------------------------------------------------------
#define KL_E (64*136)     // K tile [64][136] shorts
#define VL_E (128*72)     // V tile [128][72] shorts ([c][k])
#define SMEM_SH (18432 + 512 + 128)  // 36864B epi staging + lrb(1KB) + invL(256B)

__global__ __launch_bounds__(256,2) void attn_kernel(
    const unsigned short* __restrict__ qkv,
    unsigned short* __restrict__ Og)
{
  __shared__ __align__(16) unsigned short smem[SMEM_SH]; // 38144 B
  unsigned short (*Kl)[136] = (unsigned short(*)[136])smem;
  unsigned short (*Vl)[72]  = (unsigned short(*)[72])(smem + KL_E);
  float* lrb  = (float*)(smem + 18432);        // [4 wv][64 q]
  float* invL = (float*)(smem + 18432 + 512);  // [64 q]

  const int qt = blockIdx.x;
  const int b  = blockIdx.y;
  const int t  = blockIdx.z;
  const size_t TS = (size_t)NB*HW*CD;
  const unsigned short* Q = qkv + (size_t)b*HW*CD;
  const unsigned short* K = qkv + TS*(size_t)(1 + 2*t) + (size_t)b*HW*CD;
  const unsigned short* V = qkv + TS*(size_t)(2 + 2*t) + (size_t)b*CD*HW;

  const int tid  = threadIdx.x;
  const int wv_  = tid >> 6;
  const int lane = tid & 63;
  const int m    = lane & 15;
  const int quad = lane >> 4;
  const int q0   = qt*64;              // all 4 waves share the same 64 q rows

  // Q B-fragments for 4 q-subtiles (iter-invariant, register-resident)
  short8 qf[4][4];                     // [qs][dk]
#pragma unroll
  for (int qs=0;qs<4;qs++){
    const unsigned short* qr = Q + (size_t)(q0 + qs*16 + m)*CD + quad*8;
#pragma unroll
    for (int dk=0;dk<4;dk++) qf[qs][dk] = *(const short8*)(qr + dk*32);
  }

  floatx4 Oc[8][4];                    // k-partial O^T: [ct][qs]
#pragma unroll
  for (int i=0;i<8;i++)
#pragma unroll
    for (int j=0;j<4;j++) Oc[i][j] = (floatx4)0.f;
  float lr[4] = {0.f,0.f,0.f,0.f};     // per-lane denom partials per qs

  const unsigned short* kg = K + (size_t)(tid>>4)*CD + (tid&15)*8;
  const unsigned short* vg = V + (size_t)(tid>>3)*HW + (tid&7)*8;
  unsigned short* klds = &Kl[tid>>4][(tid&15)*8];
  unsigned short* vlds = &Vl[tid>>3][(tid&7)*8];

  for (int kt = 0; kt < NT; kt++){
    // global loads issued BEFORE the barrier (they don't touch LDS)
    short8 kr[4], vr[4];
#pragma unroll
    for (int i=0;i<4;i++) kr[i] = *(const short8*)(kg + (size_t)i*16*CD);
#pragma unroll
    for (int i=0;i<4;i++) vr[i] = *(const short8*)(vg + (size_t)i*32*HW);
    kg += 64*CD; vg += 64;
    if (kt) __syncthreads();           // all waves done reading prev tile
#pragma unroll
    for (int i=0;i<4;i++) *(short8*)(klds + i*16*136) = kr[i];
#pragma unroll
    for (int i=0;i<4;i++) *(short8*)(vlds + i*32*72)  = vr[i];
    __syncthreads();

    // QK: S^T[wv's 16k][64q]. A-frag rows = wv*16+m; read once (K tile x1).
    short8 af[4];
#pragma unroll
    for (int dk=0;dk<4;dk++)
      af[dk] = *(const short8*)&Kl[wv_*16 + m][dk*32 + quad*8];

    short4v pfv[4];
#pragma unroll
    for (int qs=0;qs<4;qs++){
      floatx4 acc = (floatx4)0.f;
#pragma unroll
      for (int dk=0;dk<4;dk++)
        acc = __builtin_amdgcn_mfma_f32_16x16x32_bf16(af[dk], qf[qs][dk], acc, 0,0,0);
      union { float f; unsigned u; } c0, c1, c2, c3;
      c0.f = __builtin_amdgcn_exp2f(acc[0]);
      c1.f = __builtin_amdgcn_exp2f(acc[1]);
      c2.f = __builtin_amdgcn_exp2f(acc[2]);
      c3.f = __builtin_amdgcn_exp2f(acc[3]);
      lr[qs] += (c0.f + c1.f) + (c2.f + c3.f);
      union { unsigned u[2]; short4v s; } pk;
      pk.u[0] = (c1.u & 0xFFFF0000u) | (c0.u >> 16);   // truncate-pack, k ascending
      pk.u[1] = (c3.u & 0xFFFF0000u) | (c2.u >> 16);
      pfv[qs] = pk.s;
    }

    // PV (K=16): O^T[c][q] += V^T[c][wv's 16k] * P^T. A-frag = b64 from Vl;
    // B-frag = lane's own pfv (fragment-layout identity). V tile read x1.
#pragma unroll
    for (int ct=0;ct<8;ct++){
      short4v vf = *(const short4v*)&Vl[ct*16 + m][wv_*16 + quad*4];
#pragma unroll
      for (int qs=0;qs<4;qs++)
        Oc[ct][qs] = MFMA16(vf, pfv[qs], Oc[ct][qs]);
    }
  }

  // ---- epilogue: cross-wave reduction of lr and O partials ----
  // denom: sum over quads (each quad held different k) -> wave total per (qs,m)
#pragma unroll
  for (int qs=0;qs<4;qs++){
    lr[qs] += __shfl_xor(lr[qs], 16, 64);
    lr[qs] += __shfl_xor(lr[qs], 32, 64);
  }
  if (quad == 0){
#pragma unroll
    for (int qs=0;qs<4;qs++) lrb[wv_*64 + qs*16 + m] = lr[qs];
  }
  __syncthreads();
  if (tid < 64)
    invL[tid] = 1.f/(lrb[tid] + lrb[64+tid] + lrb[128+tid] + lrb[192+tid]);
  __syncthreads();

  // O: 4 rounds over 32-channel quarters; stage [4 wv][64 q][36] f32, sum, store
  float* Of = (float*)smem;            // overlaps Kl/Vl (all reads done)
  unsigned short* ob = Og + ((size_t)t*NB + b)*HW*CD + (size_t)q0*CD;
  const int qlr = wv_*16 + (lane>>2);  // q row this lane reduces
  const int c8  = (lane&3)*8;
#pragma unroll
  for (int rd=0; rd<4; rd++){
#pragma unroll
    for (int cc=0; cc<2; cc++){
#pragma unroll
      for (int qs=0; qs<4; qs++)
        *(floatx4*)&Of[wv_*2304 + (qs*16+m)*36 + cc*16 + quad*4] = Oc[rd*2+cc][qs];
    }
    __syncthreads();
    floatx4 s0 = (floatx4)0.f, s1 = (floatx4)0.f;
#pragma unroll
    for (int w=0; w<4; w++){
      s0 += *(const floatx4*)&Of[w*2304 + qlr*36 + c8];
      s1 += *(const floatx4*)&Of[w*2304 + qlr*36 + c8 + 4];
    }
    float iv = invL[qlr];
    short8 o;
#pragma unroll
    for (int j=0;j<4;j++){
      o[j]   = (short)f2b(s0[j]*iv);
      o[4+j] = (short)f2b(s1[j]*iv);
    }
    *(short8*)&ob[(size_t)qlr*CD + rd*32 + c8] = o;
    __syncthreads();
  }
}

// ---------------------------------------------------------------------------
// out[b,c,hw] = s[b,c,hw] + 0.5*(O1[b,hw,c] + O2[b,hw,c])  (unchanged)
// ---------------------------------------------------------------------------
__global__ __launch_bounds__(256) void combine_kernel(
    const float* __restrict__ s, const unsigned short* __restrict__ Og,
    float* __restrict__ out)
{
  __shared__ float T[32][129];
  const int b   = blockIdx.y;
  const int hw0 = blockIdx.x * 32;
  const int tid = threadIdx.x;
  const unsigned short* O1 = Og + ((size_t)b*HW + hw0)*CD;
  const unsigned short* O2 = O1 + (size_t)NB*HW*CD;
  for (int i=0;i<2;i++){
    int flat = (tid + i*256)*8;
    int row = flat >> 7, col = flat & 127;
    short8 a  = *(const short8*)(O1 + (size_t)row*CD + col);
    short8 c2 = *(const short8*)(O2 + (size_t)row*CD + col);
    for (int j=0;j<8;j++)
      T[row][col+j] = 0.5f*(b2f((unsigned short)a[j]) + b2f((unsigned short)c2[j]));
  }
  __syncthreads();
  const int c  = tid >> 1;
  const int h0 = (tid & 1)*16;
  const float* sr = s   + ((size_t)b*CD + c)*HW + hw0 + h0;
  float*     orow = out + ((size_t)b*CD + c)*HW + hw0 + h0;
  for (int j0=0;j0<16;j0+=4){
    floatx4 sv = *(const floatx4*)(sr + j0);
    floatx4 ov;
    for (int jj=0;jj<4;jj++) ov[jj] = sv[jj] + T[h0+j0+jj][c];
    *(floatx4*)(orow + j0) = ov;
  }
}

extern "C" void kernel_launch(void* const* d_in, const int* in_sizes, int n_in,
                              void* d_out, int out_size, void* d_ws, size_t ws_size,
                              hipStream_t stream)
{
  const float* s  = (const float*)d_in[0];
  const float* t1 = (const float*)d_in[1];
  const float* t2 = (const float*)d_in[2];
  const float* wq = (const float*)d_in[3];
  const float* bq = (const float*)d_in[4];
  const float* wk = (const float*)d_in[5];
  const float* bk = (const float*)d_in[6];
  const float* wv = (const float*)d_in[7];
  const float* bv = (const float*)d_in[8];
  float* out = (float*)d_out;

  unsigned short* qkv = (unsigned short*)d_ws;
  unsigned short* Og  = qkv + (size_t)5*NB*HW*CD;

  hipLaunchKernelGGL(proj_kernel,    dim3(49,8,5), dim3(256), 0, stream,
                     s,t1,t2,wq,bq,wk,bk,wv,bv,qkv);
  hipLaunchKernelGGL(attn_kernel,    dim3(49,8,2), dim3(256), 0, stream, qkv, Og);
  hipLaunchKernelGGL(combine_kernel, dim3(98,8),   dim3(256), 0, stream, s, Og, out);
}

// Round 4
// 286.988 us; speedup vs baseline: 1.0930x; 1.0015x over previous
//
#include <hip/hip_runtime.h>

#define HW 3136
#define NB 8
#define CD 128
#define NT (HW/64)
// C^-0.5 * log2(e), folded into the Q projection so attn can use exp2 directly
#define QSCALE 0.12751750206f

typedef __attribute__((ext_vector_type(8))) short short8;
typedef __attribute__((ext_vector_type(4))) short short4v;
typedef __attribute__((ext_vector_type(4))) float floatx4;
typedef __attribute__((ext_vector_type(4))) unsigned short ushort4v;

static __device__ __forceinline__ unsigned short f2b(float f){
  union { float f; unsigned u; } v; v.f = f;
  unsigned r = v.u + 0x7FFFu + ((v.u >> 16) & 1u);
  return (unsigned short)(r >> 16);
}
static __device__ __forceinline__ float b2f(unsigned short h){
  union { unsigned u; float f; } v; v.u = ((unsigned)h) << 16;
  return v.f;
}

// K=16 bf16 MFMA: builtin spelling differs across ROCm versions; hedge.
#if __has_builtin(__builtin_amdgcn_mfma_f32_16x16x16bf16_1k)
#define MFMA16(a,b,c) __builtin_amdgcn_mfma_f32_16x16x16bf16_1k(a,b,c,0,0,0)
#elif __has_builtin(__builtin_amdgcn_mfma_f32_16x16x16_bf16)
#define MFMA16(a,b,c) __builtin_amdgcn_mfma_f32_16x16x16_bf16(a,b,c,0,0,0)
#else
static __device__ __forceinline__ floatx4 mfma16_asm(short4v a, short4v b, floatx4 c){
  floatx4 d;
  asm volatile("v_mfma_f32_16x16x16_bf16 %0, %1, %2, %3\n\ts_nop 7\n\ts_nop 7"
               : "=v"(d) : "v"(a), "v"(b), "v"(c));
  return d;
}
#define MFMA16(a,b,c) mfma16_asm(a,b,c)
#endif

// ---------------------------------------------------------------------------
// 1x1 conv projections via MFMA (unchanged — control kernel)
// ---------------------------------------------------------------------------
__global__ __launch_bounds__(256) void proj_kernel(
    const float* __restrict__ s, const float* __restrict__ t1, const float* __restrict__ t2,
    const float* __restrict__ wq, const float* __restrict__ bq,
    const float* __restrict__ wk, const float* __restrict__ bk,
    const float* __restrict__ wv, const float* __restrict__ bv,
    unsigned short* __restrict__ qkv)
{
  __shared__ __align__(16) unsigned short WL[CD][136];
  __shared__ __align__(16) unsigned short xsT[64][136];
  const int job = blockIdx.z;
  const float* x; const float* w; const float* bias; float scl; int cmajor; size_t dstoff;
  switch(job){
    case 0: x=s;  w=wq; bias=bq; scl=QSCALE; cmajor=0; dstoff=0; break;
    case 1: x=t1; w=wk; bias=bk; scl=1.f;    cmajor=0; dstoff=1; break;
    case 2: x=t1; w=wv; bias=bv; scl=1.f;    cmajor=1; dstoff=2; break;
    case 3: x=t2; w=wk; bias=bk; scl=1.f;    cmajor=0; dstoff=3; break;
    default:x=t2; w=wv; bias=bv; scl=1.f;    cmajor=1; dstoff=4; break;
  }
  const size_t TS = (size_t)NB*HW*CD;
  const int b   = blockIdx.y;
  const int hw0 = blockIdx.x * 64;
  const int tid = threadIdx.x;

  for (int i = 0; i < 16; i++){
    int flat = tid + i*256;
    int o = flat >> 5, cq = (flat & 31)*4;
    floatx4 wv4 = *(const floatx4*)(w + (size_t)o*CD + cq);
    ushort4v pk;
    for (int j=0;j<4;j++) pk[j] = f2b(wv4[j]);
    *(ushort4v*)&WL[o][cq] = pk;
  }
  const float* xb = x + (size_t)b*CD*HW + hw0;
  for (int i = 0; i < 8; i++){
    int flat = (tid + i*256)*4;
    int c = flat >> 6, hh = flat & 63;
    floatx4 xv = *(const floatx4*)(xb + (size_t)c*HW + hh);
    for (int j=0;j<4;j++) xsT[hh+j][c] = f2b(xv[j]);
  }
  __syncthreads();

  const int m = tid & 15, quad = (tid >> 4) & 3, wv_ = tid >> 6;
  short8 af[4];
  for (int dk=0;dk<4;dk++)
    af[dk] = *(const short8*)&xsT[wv_*16 + m][dk*32 + quad*8];
  float bb[8];
  for (int nt=0;nt<8;nt++) bb[nt] = bias[nt*16 + m];

  unsigned short* dstK = qkv + dstoff*TS + ((size_t)b*HW + hw0)*CD;
  unsigned short* dstV = qkv + dstoff*TS + (size_t)b*CD*HW;
  for (int nt=0;nt<8;nt++){
    floatx4 acc = {bb[nt],bb[nt],bb[nt],bb[nt]};
    for (int dk=0;dk<4;dk++){
      short8 bf = *(const short8*)&WL[nt*16 + m][dk*32 + quad*8];
      acc = __builtin_amdgcn_mfma_f32_16x16x32_bf16(af[dk], bf, acc, 0,0,0);
    }
    if (!cmajor){
      for (int r=0;r<4;r++)
        dstK[(size_t)(wv_*16 + quad*4 + r)*CD + nt*16 + m] = f2b(acc[r]*scl);
    } else {
      ushort4v pk;
      for (int r=0;r<4;r++) pk[r] = f2b(acc[r]*scl);
      *(ushort4v*)&dstV[(size_t)(nt*16 + m)*HW + hw0 + wv_*16 + quad*4] = pk;
    }
  }
}

// ---------------------------------------------------------------------------
// Flash attention, async-DMA edition.
// R3 post-mortem: 252 regs/wave (124 VGPR + 128 AGPR Oc) -> 2 waves/SIMD ->
// 512 block slots for 784 blocks = 1.53 dispatch passes (occ 15.7% ~ 25%*0.63);
// plus per-iter global-load->vmcnt->write serialization (no reg budget for
// prefetch without crossing the 256-reg cliff).
// Fixes:
//  - t-fold: one block handles both teachers (grid 392 <= 512 slots, 1 pass;
//    Q-frags loaded once). XCD pinning: b = blockIdx.x&7 -> per-XCD K/V L2-hot.
//  - global_load_lds double-buffered staging (T3 2-phase, raw s_barrier +
//    counted vmcnt(8)): zero staging VGPRs, latency hidden under compute.
//  - linear LDS (required by DMA) + XOR swizzle col16 ^= (row&7), applied to
//    BOTH the DMA source address and the ds_read address (rule 21) -> 2-way max.
// LDS: K[64][128]+V[128][64] bf16 x2 buffers = 64KB (+lrb/invL) -> 2 blocks/CU,
// consistent with the reg cap.
// ---------------------------------------------------------------------------
__global__ __launch_bounds__(256,2) void attn_kernel(
    const unsigned short* __restrict__ qkv,
    unsigned short* __restrict__ Og)
{
  // shorts: K0 [0,8192) V0 [8192,16384) K1 [16384,24576) V1 [24576,32768)
  __shared__ __align__(16) unsigned short smem[32768 + 512 + 128]; // 66816 B
  float* lrb  = (float*)(smem + 32768);        // [4 wv][64 q]
  float* invL = (float*)(smem + 32768 + 512);  // [64 q]

  const int l  = blockIdx.x;       // 392 = 8 XCD-pinned b values x 49 qt
  const int b  = l & 7;
  const int qt = l >> 3;
  const size_t TS = (size_t)NB*HW*CD;
  const unsigned short* Q = qkv + (size_t)b*HW*CD;

  const int tid  = threadIdx.x;
  const int wv_  = tid >> 6;
  const int lane = tid & 63;
  const int m    = lane & 15;
  const int quad = lane >> 4;
  const int q0   = qt*64;

  // DMA source offsets (shorts), pre-swizzled so linear LDS dest + swizzled
  // ds_read agree: LDS(row, col16) holds logical col16 ^ (row&7).
  unsigned koff[4];
  {
    const int kr_ = lane >> 4, kc_ = lane & 15;
#pragma unroll
    for (int i=0;i<4;i++){
      const int krow = wv_*16 + i*4 + kr_;
      koff[i] = (unsigned)(krow*CD + ((kc_ ^ ((i*4 + kr_) & 7))*8));
    }
  }
  const int      vrow0 = wv_*32 + (lane>>3);
  const unsigned vcs   = (unsigned)(((lane&7) ^ (lane>>3))*8);

  // Q B-fragments, iter- and teacher-invariant
  short8 qf[4][4];
#pragma unroll
  for (int qs=0;qs<4;qs++){
    const unsigned short* qr = Q + (size_t)(q0 + qs*16 + m)*CD + quad*8;
#pragma unroll
    for (int dk=0;dk<4;dk++) qf[qs][dk] = *(const short8*)(qr + dk*32);
  }

#define STAGE(buf, ktile) do { \
    const unsigned short* kt_src = K + (size_t)(ktile)*64*CD; \
    const unsigned short* vt_src = V + (size_t)(ktile)*64; \
    unsigned short* kl = (unsigned short*)smem + (buf)*16384 + wv_*2048; \
    unsigned short* vl = (unsigned short*)smem + (buf)*16384 + 8192 + wv_*2048; \
    _Pragma("unroll") \
    for (int i_=0;i_<4;i_++) \
      __builtin_amdgcn_global_load_lds( \
        (const __attribute__((address_space(1))) void*)(kt_src + koff[i_]), \
        (__attribute__((address_space(3))) void*)(kl + i_*512), 16, 0, 0); \
    _Pragma("unroll") \
    for (int i_=0;i_<4;i_++) \
      __builtin_amdgcn_global_load_lds( \
        (const __attribute__((address_space(1))) void*)(vt_src + (size_t)(vrow0 + i_*8)*HW + vcs), \
        (__attribute__((address_space(3))) void*)(vl + i_*512), 16, 0, 0); \
  } while(0)

  for (int t2=0; t2<2; t2++){
    const unsigned short* K = qkv + TS*(size_t)(1 + 2*t2) + (size_t)b*HW*CD;
    const unsigned short* V = qkv + TS*(size_t)(2 + 2*t2) + (size_t)b*CD*HW;

    floatx4 Oc[8][4];                  // k-partial O^T: [ct][qs] (AGPRs)
#pragma unroll
    for (int i=0;i<8;i++)
#pragma unroll
      for (int j=0;j<4;j++) Oc[i][j] = (floatx4)0.f;
    float lr[4] = {0.f,0.f,0.f,0.f};

    STAGE(0, 0);                       // prologue: tile 0 -> buf0

    for (int kt = 0; kt < NT; kt++){
      const int cur = kt & 1;
      __builtin_amdgcn_s_barrier();    // B1: all waves done computing buf[cur^1]
      if (kt < NT-1){
        STAGE(cur^1, kt+1);            // async DMA next tile
        asm volatile("s_waitcnt vmcnt(8)" ::: "memory");  // own buf[cur] DMAs done
      } else {
        asm volatile("s_waitcnt vmcnt(0)" ::: "memory");
      }
      __builtin_amdgcn_sched_barrier(0);
      __builtin_amdgcn_s_barrier();    // B2: everyone's buf[cur] complete
      asm volatile("" ::: "memory");

      const unsigned short* Kc = (const unsigned short*)smem + cur*16384;
      const unsigned short* Vc = (const unsigned short*)smem + cur*16384 + 8192;

      // QK: S^T[wv's 16k][64q]; A-frag = own-wave K rows, swizzled read
      short8 af[4];
#pragma unroll
      for (int dk=0;dk<4;dk++)
        af[dk] = *(const short8*)&Kc[(wv_*16 + m)*128 + (((dk*4 + quad) ^ (m & 7))*8)];

      short4v pfv[4];
#pragma unroll
      for (int qs=0;qs<4;qs++){
        floatx4 acc = (floatx4)0.f;
#pragma unroll
        for (int dk=0;dk<4;dk++)
          acc = __builtin_amdgcn_mfma_f32_16x16x32_bf16(af[dk], qf[qs][dk], acc, 0,0,0);
        union { float f; unsigned u; } c0, c1, c2, c3;
        c0.f = __builtin_amdgcn_exp2f(acc[0]);
        c1.f = __builtin_amdgcn_exp2f(acc[1]);
        c2.f = __builtin_amdgcn_exp2f(acc[2]);
        c3.f = __builtin_amdgcn_exp2f(acc[3]);
        lr[qs] += (c0.f + c1.f) + (c2.f + c3.f);
        union { unsigned u[2]; short4v s; } pk;
        pk.u[0] = (c1.u & 0xFFFF0000u) | (c0.u >> 16);
        pk.u[1] = (c3.u & 0xFFFF0000u) | (c2.u >> 16);
        pfv[qs] = pk.s;
      }

      // PV (K=16): O^T += V^T[c][wv's 16k] * P^T; swizzled b64 A-frag reads
#pragma unroll
      for (int ct=0;ct<8;ct++){
        short4v vf = *(const short4v*)&Vc[(ct*16 + m)*64 +
                       (((2*wv_ + (quad>>1)) ^ (m & 7))*8) + (quad&1)*4];
#pragma unroll
        for (int qs=0;qs<4;qs++)
          Oc[ct][qs] = MFMA16(vf, pfv[qs], Oc[ct][qs]);
      }
    }

    // ---- epilogue: cross-wave reduction of lr and O partials ----
#pragma unroll
    for (int qs=0;qs<4;qs++){
      lr[qs] += __shfl_xor(lr[qs], 16, 64);
      lr[qs] += __shfl_xor(lr[qs], 32, 64);
    }
    if (quad == 0){
#pragma unroll
      for (int qs=0;qs<4;qs++) lrb[wv_*64 + qs*16 + m] = lr[qs];
    }
    __syncthreads();
    if (tid < 64)
      invL[tid] = 1.f/(lrb[tid] + lrb[64+tid] + lrb[128+tid] + lrb[192+tid]);
    __syncthreads();

    float* Of = (float*)smem;          // overlaps K/V buffers (all reads done)
    unsigned short* ob = Og + ((size_t)t2*NB + b)*HW*CD + (size_t)q0*CD;
    const int qlr = wv_*16 + (lane>>2);
    const int c8  = (lane&3)*8;
#pragma unroll
    for (int rd=0; rd<4; rd++){
#pragma unroll
      for (int cc=0; cc<2; cc++){
#pragma unroll
        for (int qs=0; qs<4; qs++)
          *(floatx4*)&Of[wv_*2304 + (qs*16+m)*36 + cc*16 + quad*4] = Oc[rd*2+cc][qs];
      }
      __syncthreads();
      floatx4 s0 = (floatx4)0.f, s1 = (floatx4)0.f;
#pragma unroll
      for (int w=0; w<4; w++){
        s0 += *(const floatx4*)&Of[w*2304 + qlr*36 + c8];
        s1 += *(const floatx4*)&Of[w*2304 + qlr*36 + c8 + 4];
      }
      float iv = invL[qlr];
      short8 o;
#pragma unroll
      for (int j=0;j<4;j++){
        o[j]   = (short)f2b(s0[j]*iv);
        o[4+j] = (short)f2b(s1[j]*iv);
      }
      *(short8*)&ob[(size_t)qlr*CD + rd*32 + c8] = o;
      __syncthreads();
    }
  }
#undef STAGE
}

// ---------------------------------------------------------------------------
// out[b,c,hw] = s[b,c,hw] + 0.5*(O1[b,hw,c] + O2[b,hw,c])  (unchanged)
// ---------------------------------------------------------------------------
__global__ __launch_bounds__(256) void combine_kernel(
    const float* __restrict__ s, const unsigned short* __restrict__ Og,
    float* __restrict__ out)
{
  __shared__ float T[32][129];
  const int b   = blockIdx.y;
  const int hw0 = blockIdx.x * 32;
  const int tid = threadIdx.x;
  const unsigned short* O1 = Og + ((size_t)b*HW + hw0)*CD;
  const unsigned short* O2 = O1 + (size_t)NB*HW*CD;
  for (int i=0;i<2;i++){
    int flat = (tid + i*256)*8;
    int row = flat >> 7, col = flat & 127;
    short8 a  = *(const short8*)(O1 + (size_t)row*CD + col);
    short8 c2 = *(const short8*)(O2 + (size_t)row*CD + col);
    for (int j=0;j<8;j++)
      T[row][col+j] = 0.5f*(b2f((unsigned short)a[j]) + b2f((unsigned short)c2[j]));
  }
  __syncthreads();
  const int c  = tid >> 1;
  const int h0 = (tid & 1)*16;
  const float* sr = s   + ((size_t)b*CD + c)*HW + hw0 + h0;
  float*     orow = out + ((size_t)b*CD + c)*HW + hw0 + h0;
  for (int j0=0;j0<16;j0+=4){
    floatx4 sv = *(const floatx4*)(sr + j0);
    floatx4 ov;
    for (int jj=0;jj<4;jj++) ov[jj] = sv[jj] + T[h0+j0+jj][c];
    *(floatx4*)(orow + j0) = ov;
  }
}

extern "C" void kernel_launch(void* const* d_in, const int* in_sizes, int n_in,
                              void* d_out, int out_size, void* d_ws, size_t ws_size,
                              hipStream_t stream)
{
  const float* s  = (const float*)d_in[0];
  const float* t1 = (const float*)d_in[1];
  const float* t2 = (const float*)d_in[2];
  const float* wq = (const float*)d_in[3];
  const float* bq = (const float*)d_in[4];
  const float* wk = (const float*)d_in[5];
  const float* bk = (const float*)d_in[6];
  const float* wv = (const float*)d_in[7];
  const float* bv = (const float*)d_in[8];
  float* out = (float*)d_out;

  unsigned short* qkv = (unsigned short*)d_ws;
  unsigned short* Og  = qkv + (size_t)5*NB*HW*CD;

  hipLaunchKernelGGL(proj_kernel,    dim3(49,8,5), dim3(256), 0, stream,
                     s,t1,t2,wq,bq,wk,bk,wv,bv,qkv);
  hipLaunchKernelGGL(attn_kernel,    dim3(392),    dim3(256), 0, stream, qkv, Og);
  hipLaunchKernelGGL(combine_kernel, dim3(98,8),   dim3(256), 0, stream, s, Og, out);
}